// Round 1
// baseline (197.837 us; speedup 1.0000x reference)
//
#include <hip/hip_runtime.h>
#include <hip/hip_bf16.h>

#define OUTF 4096
#define INF  4096
#define BATCH 128

// ---- generic 32x32 tiled transpose: in[R][C] -> out[C][R] (R,C % 32 == 0) ----
__global__ __launch_bounds__(1024) void k_transpose32(const float* __restrict__ in,
                                                      float* __restrict__ out,
                                                      int R, int C) {
  __shared__ float t[32][33];
  int bx = blockIdx.x * 32, by = blockIdx.y * 32;
  t[threadIdx.y][threadIdx.x] = in[(size_t)(by + threadIdx.y) * C + (bx + threadIdx.x)];
  __syncthreads();
  out[(size_t)(bx + threadIdx.y) * R + (by + threadIdx.x)] = t[threadIdx.x][threadIdx.y];
}

// ---- histogram of rows into counts[OUTF], LDS-staged ----
__global__ __launch_bounds__(256) void k_hist(const int* __restrict__ rows, int n,
                                              int* __restrict__ counts) {
  __shared__ int h[OUTF];
  for (int i = threadIdx.x; i < OUTF; i += blockDim.x) h[i] = 0;
  __syncthreads();
  int stride = gridDim.x * blockDim.x;
  for (int i = blockIdx.x * blockDim.x + threadIdx.x; i < n; i += stride)
    atomicAdd(&h[rows[i]], 1);
  __syncthreads();
  for (int i = threadIdx.x; i < OUTF; i += blockDim.x) {
    int c = h[i];
    if (c) atomicAdd(&counts[i], c);
  }
}

// ---- exclusive scan of counts[4096] -> rowStart[4097], rowCur[4096] ----
__global__ __launch_bounds__(1024) void k_scan(const int* __restrict__ counts,
                                               int* __restrict__ rowStart,
                                               int* __restrict__ rowCur) {
  __shared__ int tot[1024];
  int t = threadIdx.x;
  int4 c = ((const int4*)counts)[t];
  int mySum = c.x + c.y + c.z + c.w;
  tot[t] = mySum;
  __syncthreads();
  for (int off = 1; off < 1024; off <<= 1) {
    int v = (t >= off) ? tot[t - off] : 0;
    __syncthreads();
    tot[t] += v;
    __syncthreads();
  }
  int excl = tot[t] - mySum;  // exclusive prefix of thread totals
  int4 rs;
  rs.x = excl;
  rs.y = excl + c.x;
  rs.z = excl + c.x + c.y;
  rs.w = excl + c.x + c.y + c.z;
  ((int4*)rowStart)[t] = rs;
  ((int4*)rowCur)[t]   = rs;
  if (t == 1023) rowStart[4096] = tot[1023];
}

// ---- scatter (val,col) pairs into row-bucketed order via atomic cursors ----
__global__ __launch_bounds__(256) void k_scatter(const float* __restrict__ vals,
                                                 const int* __restrict__ rows,
                                                 const int* __restrict__ cols, int n,
                                                 int* __restrict__ rowCur,
                                                 int2* __restrict__ svc) {
  int i = blockIdx.x * blockDim.x + threadIdx.x;
  if (i >= n) return;
  int r = rows[i];
  int p = atomicAdd(&rowCur[r], 1);
  int2 vc;
  vc.x = __float_as_int(vals[i]);
  vc.y = cols[i];
  svc[p] = vc;
}

// ---- CSR SpMM: one 64-lane wave per output row; float2 (2 batch elems)/lane ----
__global__ __launch_bounds__(64) void k_spmm(const int2* __restrict__ svc,
                                             const int* __restrict__ rowStart,
                                             const float* __restrict__ XT,
                                             float* __restrict__ outT) {
  int r = blockIdx.x;
  int lane = threadIdx.x;  // 0..63, covers 128 batch via float2
  int s = rowStart[r], e = rowStart[r + 1];
  const float2* __restrict__ XT2 = (const float2*)XT;
  float2 acc0 = make_float2(0.f, 0.f);
  float2 acc1 = make_float2(0.f, 0.f);
  int p = s;
#pragma unroll 2
  for (; p + 1 < e; p += 2) {
    int2 a = svc[p];
    int2 b = svc[p + 1];
    float2 xa = XT2[a.y * 64 + lane];
    float2 xb = XT2[b.y * 64 + lane];
    float va = __int_as_float(a.x);
    float vb = __int_as_float(b.x);
    acc0.x += va * xa.x; acc0.y += va * xa.y;
    acc1.x += vb * xb.x; acc1.y += vb * xb.y;
  }
  if (p < e) {
    int2 a = svc[p];
    float2 xa = XT2[a.y * 64 + lane];
    float va = __int_as_float(a.x);
    acc0.x += va * xa.x; acc0.y += va * xa.y;
  }
  acc0.x += acc1.x; acc0.y += acc1.y;
  ((float2*)outT)[r * 64 + lane] = acc0;
}

// ---- safety-net fallback if ws is too small: direct atomics ----
__global__ __launch_bounds__(256) void k_fallback(const float* __restrict__ X,
                                                  const float* __restrict__ vals,
                                                  const int* __restrict__ rows,
                                                  const int* __restrict__ cols, int n,
                                                  float* __restrict__ out) {
  int k = blockIdx.x * blockDim.x + threadIdx.x;
  if (k >= n) return;
  float v = vals[k];
  int r = rows[k], c = cols[k];
  for (int b = 0; b < BATCH; ++b)
    atomicAdd(&out[(size_t)b * OUTF + r], v * X[(size_t)b * INF + c]);
}

extern "C" void kernel_launch(void* const* d_in, const int* in_sizes, int n_in,
                              void* d_out, int out_size, void* d_ws, size_t ws_size,
                              hipStream_t stream) {
  const float* X  = (const float*)d_in[0];
  const float* Wv = (const float*)d_in[1];
  const int*   Wr = (const int*)d_in[2];
  const int*   Wc = (const int*)d_in[3];
  float* out = (float*)d_out;
  const int nnz = in_sizes[1];

  char* ws = (char*)d_ws;
  const size_t OFF_XT   = 0;                                   // 2 MB
  const size_t OFF_OUTT = OFF_XT   + (size_t)INF * BATCH * 4;  // 2 MB
  const size_t OFF_SVC  = OFF_OUTT + (size_t)OUTF * BATCH * 4; // nnz*8 = 8 MB
  const size_t OFF_CNT  = OFF_SVC  + (size_t)nnz * 8;          // 16 KB
  const size_t OFF_RS   = OFF_CNT  + (size_t)OUTF * 4;         // 16400 B (padded)
  const size_t OFF_RC   = OFF_RS   + (size_t)(OUTF + 4) * 4;   // 16 KB
  const size_t NEEDED   = OFF_RC   + (size_t)OUTF * 4;

  if (ws_size < NEEDED) {
    hipMemsetAsync(d_out, 0, (size_t)out_size * 4, stream);
    k_fallback<<<dim3((nnz + 255) / 256), dim3(256), 0, stream>>>(X, Wv, Wr, Wc, nnz, out);
    return;
  }

  float* XT      = (float*)(ws + OFF_XT);
  float* outT    = (float*)(ws + OFF_OUTT);
  int2*  svc     = (int2*)(ws + OFF_SVC);
  int*   counts  = (int*)(ws + OFF_CNT);
  int*   rowStart= (int*)(ws + OFF_RS);
  int*   rowCur  = (int*)(ws + OFF_RC);

  hipMemsetAsync(counts, 0, (size_t)OUTF * 4, stream);
  k_transpose32<<<dim3(INF / 32, BATCH / 32), dim3(32, 32), 0, stream>>>(X, XT, BATCH, INF);
  k_hist<<<dim3(128), dim3(256), 0, stream>>>(Wr, nnz, counts);
  k_scan<<<dim3(1), dim3(1024), 0, stream>>>(counts, rowStart, rowCur);
  k_scatter<<<dim3((nnz + 255) / 256), dim3(256), 0, stream>>>(Wv, Wr, Wc, nnz, rowCur, svc);
  k_spmm<<<dim3(OUTF), dim3(64), 0, stream>>>(svc, rowStart, XT, outT);
  k_transpose32<<<dim3(BATCH / 32, OUTF / 32), dim3(32, 32), 0, stream>>>(outT, out, OUTF, BATCH);
}

// Round 2
// 196.480 us; speedup vs baseline: 1.0069x; 1.0069x over previous
//
#include <hip/hip_runtime.h>
#include <hip/hip_bf16.h>

#define OUTF 4096
#define INF  4096
#define BATCH 128
#define NB 64          // localsort blocks (private chunks)
#define SORT_T 512     // threads in localsort block

// ---- generic 32x32 tiled transpose: in[R][C] -> out[C][R] (R,C % 32 == 0) ----
__global__ __launch_bounds__(1024) void k_transpose32(const float* __restrict__ in,
                                                      float* __restrict__ out,
                                                      int R, int C) {
  __shared__ float t[32][33];
  int bx = blockIdx.x * 32, by = blockIdx.y * 32;
  t[threadIdx.y][threadIdx.x] = in[(size_t)(by + threadIdx.y) * C + (bx + threadIdx.x)];
  __syncthreads();
  out[(size_t)(bx + threadIdx.y) * R + (by + threadIdx.x)] = t[threadIdx.x][threadIdx.y];
}

// ---- block-local counting sort: each block sorts its private chunk by row ----
// Emits sval/scol in (block, row) order + segStart[blk][OUTF+1] (absolute idx).
// All scatter writes land in the block's private contiguous range -> no
// cross-XCD line bouncing (R1 lesson: 59MB writeback for 8MB payload).
__global__ __launch_bounds__(SORT_T) void k_localsort(
    const float* __restrict__ vals, const int* __restrict__ rows,
    const int* __restrict__ cols, int nnz, int chunk,
    float* __restrict__ sval, unsigned short* __restrict__ scol,
    int* __restrict__ segStart) {
  __shared__ int hist[OUTF];      // 16 KB
  __shared__ int cursor[OUTF];    // 16 KB
  __shared__ int scanTmp[SORT_T]; // 2 KB
  const int blk = blockIdx.x;
  const int t = threadIdx.x;
  const int s = blk * chunk;
  const int e = min(nnz, s + chunk);

  for (int i = t; i < OUTF; i += SORT_T) hist[i] = 0;
  __syncthreads();
  for (int i = s + t; i < e; i += SORT_T)
    atomicAdd(&hist[rows[i]], 1);
  __syncthreads();

  // per-thread serial scan over 8 consecutive bins
  const int BINS = OUTF / SORT_T;  // 8
  int base = t * BINS;
  int loc[BINS];
  int sum = 0;
#pragma unroll
  for (int j = 0; j < BINS; ++j) { loc[j] = sum; sum += hist[base + j]; }
  scanTmp[t] = sum;
  __syncthreads();
  // Hillis-Steele inclusive scan over SORT_T partials
  for (int off = 1; off < SORT_T; off <<= 1) {
    int v = (t >= off) ? scanTmp[t - off] : 0;
    __syncthreads();
    scanTmp[t] += v;
    __syncthreads();
  }
  int excl = scanTmp[t] - sum;  // exclusive prefix of this thread's bins
#pragma unroll
  for (int j = 0; j < BINS; ++j) {
    int abs_start = s + excl + loc[j];
    segStart[blk * (OUTF + 1) + base + j] = abs_start;
    cursor[base + j] = abs_start;
  }
  if (t == 0) segStart[blk * (OUTF + 1) + OUTF] = e;
  __syncthreads();

  // scatter into private range [s, e)
  for (int i = s + t; i < e; i += SORT_T) {
    int r = rows[i];
    int p = atomicAdd(&cursor[r], 1);
    sval[p] = vals[i];
    scol[p] = (unsigned short)cols[i];
  }
}

// ---- segmented-CSR SpMM: one 64-lane wave per output row ----
// Row r's entries live in NB segments; segment bounds are wave-uniform
// (r = blockIdx.x) -> scalar loads. Each lane holds 2 batch elems (float2).
__global__ __launch_bounds__(64) void k_spmm(
    const float* __restrict__ sval, const unsigned short* __restrict__ scol,
    const int* __restrict__ segStart, const float* __restrict__ XT,
    float* __restrict__ outT) {
  const int r = blockIdx.x;
  const int lane = threadIdx.x;
  const float2* __restrict__ XT2 = (const float2*)XT;
  float2 acc0 = make_float2(0.f, 0.f);
  float2 acc1 = make_float2(0.f, 0.f);
  for (int blk = 0; blk < NB; ++blk) {
    const int* sb = segStart + blk * (OUTF + 1) + r;
    int ss = sb[0];
    int ee = sb[1];
    int p = ss;
    for (; p + 1 < ee; p += 2) {
      float va = sval[p], vb = sval[p + 1];
      int ca = scol[p], cb = scol[p + 1];
      float2 xa = XT2[ca * 64 + lane];
      float2 xb = XT2[cb * 64 + lane];
      acc0.x += va * xa.x; acc0.y += va * xa.y;
      acc1.x += vb * xb.x; acc1.y += vb * xb.y;
    }
    if (p < ee) {
      float va = sval[p];
      int ca = scol[p];
      float2 xa = XT2[ca * 64 + lane];
      acc0.x += va * xa.x; acc0.y += va * xa.y;
    }
  }
  acc0.x += acc1.x; acc0.y += acc1.y;
  ((float2*)outT)[r * 64 + lane] = acc0;
}

// ---- safety-net fallback if ws is too small: direct atomics ----
__global__ __launch_bounds__(256) void k_fallback(const float* __restrict__ X,
                                                  const float* __restrict__ vals,
                                                  const int* __restrict__ rows,
                                                  const int* __restrict__ cols, int n,
                                                  float* __restrict__ out) {
  int k = blockIdx.x * blockDim.x + threadIdx.x;
  if (k >= n) return;
  float v = vals[k];
  int r = rows[k], c = cols[k];
  for (int b = 0; b < BATCH; ++b)
    atomicAdd(&out[(size_t)b * OUTF + r], v * X[(size_t)b * INF + c]);
}

extern "C" void kernel_launch(void* const* d_in, const int* in_sizes, int n_in,
                              void* d_out, int out_size, void* d_ws, size_t ws_size,
                              hipStream_t stream) {
  const float* X  = (const float*)d_in[0];
  const float* Wv = (const float*)d_in[1];
  const int*   Wr = (const int*)d_in[2];
  const int*   Wc = (const int*)d_in[3];
  float* out = (float*)d_out;
  const int nnz = in_sizes[1];

  char* ws = (char*)d_ws;
  const size_t OFF_XT   = 0;                                     // 2 MB
  const size_t OFF_OUTT = OFF_XT   + (size_t)INF * BATCH * 4;    // 2 MB
  const size_t OFF_SVAL = OFF_OUTT + (size_t)OUTF * BATCH * 4;   // nnz*4 = 4 MB
  const size_t OFF_SEG  = OFF_SVAL + (size_t)nnz * 4;            // NB*(OUTF+1)*4 ~ 1 MB
  const size_t OFF_SCOL = OFF_SEG  + (size_t)NB * (OUTF + 1) * 4;// nnz*2 = 2 MB
  const size_t NEEDED   = OFF_SCOL + (size_t)nnz * 2;            // ~11.1 MB total

  if (ws_size < NEEDED) {
    hipMemsetAsync(d_out, 0, (size_t)out_size * 4, stream);
    k_fallback<<<dim3((nnz + 255) / 256), dim3(256), 0, stream>>>(X, Wv, Wr, Wc, nnz, out);
    return;
  }

  float*          XT       = (float*)(ws + OFF_XT);
  float*          outT     = (float*)(ws + OFF_OUTT);
  float*          sval     = (float*)(ws + OFF_SVAL);
  int*            segStart = (int*)(ws + OFF_SEG);
  unsigned short* scol     = (unsigned short*)(ws + OFF_SCOL);

  const int chunk = (nnz + NB - 1) / NB;

  k_transpose32<<<dim3(INF / 32, BATCH / 32), dim3(32, 32), 0, stream>>>(X, XT, BATCH, INF);
  k_localsort<<<dim3(NB), dim3(SORT_T), 0, stream>>>(Wv, Wr, Wc, nnz, chunk, sval, scol, segStart);
  k_spmm<<<dim3(OUTF), dim3(64), 0, stream>>>(sval, scol, segStart, XT, outT);
  k_transpose32<<<dim3(BATCH / 32, OUTF / 32), dim3(32, 32), 0, stream>>>(outT, out, OUTF, BATCH);
}

// Round 3
// 152.237 us; speedup vs baseline: 1.2995x; 1.2906x over previous
//
#include <hip/hip_runtime.h>
#include <hip/hip_bf16.h>

#define OUTF 4096
#define INF  4096
#define BATCH 128
#define NB 128         // localsort blocks (private chunks)
#define SORT_T 512     // threads per localsort block

// ---- generic 32x32 tiled transpose: in[R][C] -> out[C][R] (R,C % 32 == 0) ----
__global__ __launch_bounds__(1024) void k_transpose32(const float* __restrict__ in,
                                                      float* __restrict__ out,
                                                      int R, int C) {
  __shared__ float t[32][33];
  int bx = blockIdx.x * 32, by = blockIdx.y * 32;
  t[threadIdx.y][threadIdx.x] = in[(size_t)(by + threadIdx.y) * C + (bx + threadIdx.x)];
  __syncthreads();
  out[(size_t)(bx + threadIdx.y) * R + (by + threadIdx.x)] = t[threadIdx.x][threadIdx.y];
}

// ---- block-local counting sort into private contiguous range (no bounce) ----
__global__ __launch_bounds__(SORT_T) void k_localsort(
    const float* __restrict__ vals, const int* __restrict__ rows,
    const int* __restrict__ cols, int nnz, int chunk,
    int2* __restrict__ svc, int* __restrict__ segStart) {
  __shared__ int hist[OUTF];      // 16 KB
  __shared__ int cursor[OUTF];    // 16 KB
  __shared__ int scanTmp[SORT_T];
  const int blk = blockIdx.x;
  const int t = threadIdx.x;
  const int s = blk * chunk;
  const int e = min(nnz, s + chunk);

  for (int i = t; i < OUTF; i += SORT_T) hist[i] = 0;
  __syncthreads();
  for (int i = s + t; i < e; i += SORT_T)
    atomicAdd(&hist[rows[i]], 1);
  __syncthreads();

  const int BINS = OUTF / SORT_T;  // 8
  int base = t * BINS;
  int loc[BINS];
  int sum = 0;
#pragma unroll
  for (int j = 0; j < BINS; ++j) { loc[j] = sum; sum += hist[base + j]; }
  scanTmp[t] = sum;
  __syncthreads();
  for (int off = 1; off < SORT_T; off <<= 1) {
    int v = (t >= off) ? scanTmp[t - off] : 0;
    __syncthreads();
    scanTmp[t] += v;
    __syncthreads();
  }
  int excl = scanTmp[t] - sum;
#pragma unroll
  for (int j = 0; j < BINS; ++j) {
    int abs_start = s + excl + loc[j];
    segStart[blk * (OUTF + 1) + base + j] = abs_start;
    cursor[base + j] = abs_start;
  }
  if (t == 0) segStart[blk * (OUTF + 1) + OUTF] = e;
  __syncthreads();

  // single 8B packed store per entry, into private range [s, e)
  for (int i = s + t; i < e; i += SORT_T) {
    int r = rows[i];
    int p = atomicAdd(&cursor[r], 1);
    int2 vc;
    vc.x = __float_as_int(vals[i]);
    vc.y = cols[i];
    svc[p] = vc;
  }
}

// ---- per-row total counts: count[r] = sum over blocks of segment length ----
__global__ __launch_bounds__(256) void k_counts(const int* __restrict__ segStart,
                                                int* __restrict__ count) {
  int r = blockIdx.x * 256 + threadIdx.x;  // 0..4095, coalesced per blk iter
  int c = 0;
  for (int b = 0; b < NB; ++b) {
    const int* sp = segStart + b * (OUTF + 1) + r;
    c += sp[1] - sp[0];
  }
  count[r] = c;
}

// ---- exclusive scan of count[4096] -> rowPtr[4097] ----
__global__ __launch_bounds__(1024) void k_scan(const int* __restrict__ counts,
                                               int* __restrict__ rowPtr) {
  __shared__ int tot[1024];
  int t = threadIdx.x;
  int4 c = ((const int4*)counts)[t];
  int mySum = c.x + c.y + c.z + c.w;
  tot[t] = mySum;
  __syncthreads();
  for (int off = 1; off < 1024; off <<= 1) {
    int v = (t >= off) ? tot[t - off] : 0;
    __syncthreads();
    tot[t] += v;
    __syncthreads();
  }
  int excl = tot[t] - mySum;
  int4 rs;
  rs.x = excl;
  rs.y = excl + c.x;
  rs.z = excl + c.x + c.y;
  rs.w = excl + c.x + c.y + c.z;
  ((int4*)rowPtr)[t] = rs;
  if (t == 1023) rowPtr[4096] = tot[1023];
}

// ---- repack: gather each row's NB segments into one contiguous csr range ----
// Reads are the scattered side (no bounce); writes are private contiguous.
__global__ __launch_bounds__(64) void k_repack(const int2* __restrict__ svc,
                                               const int* __restrict__ segStart,
                                               const int* __restrict__ rowPtr,
                                               int2* __restrict__ csr) {
  const int r = blockIdx.x;
  const int lane = threadIdx.x;
  // NB=128: each lane owns segments lane and lane+64
  int s0 = segStart[lane * (OUTF + 1) + r];
  int e0 = segStart[lane * (OUTF + 1) + r + 1];
  int s1 = segStart[(lane + 64) * (OUTF + 1) + r];
  int e1 = segStart[(lane + 64) * (OUTF + 1) + r + 1];
  int len0 = e0 - s0, len1 = e1 - s1;
  int tot = len0 + len1;
  int v = tot;
#pragma unroll
  for (int off = 1; off < 64; off <<= 1) {
    int u = __shfl_up(v, off);
    if (lane >= off) v += u;
  }
  int dst = rowPtr[r] + v - tot;  // exclusive prefix
  for (int k = 0; k < len0; ++k) csr[dst + k] = svc[s0 + k];
  dst += len0;
  for (int k = 0; k < len1; ++k) csr[dst + k] = svc[s1 + k];
}

// ---- CSR SpMM: wave per row, 8-wide batches, prefetch next batch ----
// Entry loads are wave-uniform (-> s_load); 8 independent XT gathers in
// flight + 8 prefetch loads; 4 independent accumulators break FMA chains.
__global__ __launch_bounds__(64) void k_spmm(const int2* __restrict__ csr,
                                             const int* __restrict__ rowPtr,
                                             const float* __restrict__ XT,
                                             float* __restrict__ outT) {
  const int r = blockIdx.x;
  const int lane = threadIdx.x;
  const float2* __restrict__ XT2 = (const float2*)XT;
  int p = rowPtr[r];
  const int e = rowPtr[r + 1];
  float2 acc[4];
#pragma unroll
  for (int j = 0; j < 4; ++j) acc[j] = make_float2(0.f, 0.f);

  int2 cur[8], nxt[8];
  if (p + 8 <= e) {
#pragma unroll
    for (int j = 0; j < 8; ++j) cur[j] = csr[p + j];
  }
  while (p + 16 <= e) {
#pragma unroll
    for (int j = 0; j < 8; ++j) nxt[j] = csr[p + 8 + j];
    float2 x[8];
#pragma unroll
    for (int j = 0; j < 8; ++j) x[j] = XT2[cur[j].y * 64 + lane];
#pragma unroll
    for (int j = 0; j < 8; ++j) {
      float v = __int_as_float(cur[j].x);
      acc[j & 3].x = fmaf(v, x[j].x, acc[j & 3].x);
      acc[j & 3].y = fmaf(v, x[j].y, acc[j & 3].y);
    }
#pragma unroll
    for (int j = 0; j < 8; ++j) cur[j] = nxt[j];
    p += 8;
  }
  if (p + 8 <= e) {  // drain the last prefetched full batch
    float2 x[8];
#pragma unroll
    for (int j = 0; j < 8; ++j) x[j] = XT2[cur[j].y * 64 + lane];
#pragma unroll
    for (int j = 0; j < 8; ++j) {
      float v = __int_as_float(cur[j].x);
      acc[j & 3].x = fmaf(v, x[j].x, acc[j & 3].x);
      acc[j & 3].y = fmaf(v, x[j].y, acc[j & 3].y);
    }
    p += 8;
  }
  for (; p < e; ++p) {  // tail < 8
    int2 t = csr[p];
    float2 x = XT2[t.y * 64 + lane];
    float v = __int_as_float(t.x);
    acc[0].x = fmaf(v, x.x, acc[0].x);
    acc[0].y = fmaf(v, x.y, acc[0].y);
  }
  float2 res;
  res.x = acc[0].x + acc[1].x + acc[2].x + acc[3].x;
  res.y = acc[0].y + acc[1].y + acc[2].y + acc[3].y;
  ((float2*)outT)[r * 64 + lane] = res;
}

// ---- safety-net fallback if ws is too small: direct atomics ----
__global__ __launch_bounds__(256) void k_fallback(const float* __restrict__ X,
                                                  const float* __restrict__ vals,
                                                  const int* __restrict__ rows,
                                                  const int* __restrict__ cols, int n,
                                                  float* __restrict__ out) {
  int k = blockIdx.x * blockDim.x + threadIdx.x;
  if (k >= n) return;
  float v = vals[k];
  int r = rows[k], c = cols[k];
  for (int b = 0; b < BATCH; ++b)
    atomicAdd(&out[(size_t)b * OUTF + r], v * X[(size_t)b * INF + c]);
}

extern "C" void kernel_launch(void* const* d_in, const int* in_sizes, int n_in,
                              void* d_out, int out_size, void* d_ws, size_t ws_size,
                              hipStream_t stream) {
  const float* X  = (const float*)d_in[0];
  const float* Wv = (const float*)d_in[1];
  const int*   Wr = (const int*)d_in[2];
  const int*   Wc = (const int*)d_in[3];
  float* out = (float*)d_out;
  const int nnz = in_sizes[1];

  char* ws = (char*)d_ws;
  const size_t OFF_XT   = 0;                                      // 2 MB
  const size_t OFF_OUTT = OFF_XT   + (size_t)INF * BATCH * 4;     // 2 MB
  const size_t OFF_SVC  = OFF_OUTT + (size_t)OUTF * BATCH * 4;    // nnz*8 = 8 MB
  const size_t OFF_CSR  = OFF_SVC  + (size_t)nnz * 8;             // nnz*8 = 8 MB
  const size_t OFF_SEG  = OFF_CSR  + (size_t)nnz * 8;             // NB*(OUTF+1)*4 ~ 2.1 MB
  const size_t OFF_CNT  = OFF_SEG  + (size_t)NB * (OUTF + 1) * 4; // 16 KB
  const size_t OFF_RP   = OFF_CNT  + (size_t)OUTF * 4;            // 16.4 KB
  const size_t NEEDED   = OFF_RP   + (size_t)(OUTF + 4) * 4;      // ~22.2 MB

  if (ws_size < NEEDED) {
    hipMemsetAsync(d_out, 0, (size_t)out_size * 4, stream);
    k_fallback<<<dim3((nnz + 255) / 256), dim3(256), 0, stream>>>(X, Wv, Wr, Wc, nnz, out);
    return;
  }

  float* XT      = (float*)(ws + OFF_XT);
  float* outT    = (float*)(ws + OFF_OUTT);
  int2*  svc     = (int2*)(ws + OFF_SVC);
  int2*  csr     = (int2*)(ws + OFF_CSR);
  int*   segStart= (int*)(ws + OFF_SEG);
  int*   count   = (int*)(ws + OFF_CNT);
  int*   rowPtr  = (int*)(ws + OFF_RP);

  const int chunk = (nnz + NB - 1) / NB;  // 8192

  k_transpose32<<<dim3(INF / 32, BATCH / 32), dim3(32, 32), 0, stream>>>(X, XT, BATCH, INF);
  k_localsort<<<dim3(NB), dim3(SORT_T), 0, stream>>>(Wv, Wr, Wc, nnz, chunk, svc, segStart);
  k_counts<<<dim3(OUTF / 256), dim3(256), 0, stream>>>(segStart, count);
  k_scan<<<dim3(1), dim3(1024), 0, stream>>>(count, rowPtr);
  k_repack<<<dim3(OUTF), dim3(64), 0, stream>>>(svc, segStart, rowPtr, csr);
  k_spmm<<<dim3(OUTF), dim3(64), 0, stream>>>(csr, rowPtr, XT, outT);
  k_transpose32<<<dim3(BATCH / 32, OUTF / 32), dim3(32, 32), 0, stream>>>(outT, out, OUTF, BATCH);
}